// Round 4
// baseline (317.907 us; speedup 1.0000x reference)
//
#include <hip/hip_runtime.h>
#include <hip/hip_bf16.h>

// MultiScaleEdgeBuilder: all-pairs mask + 16-wide Gaussian RBF.
// N=2048, NUM_RBF=16, CUTOFF=8.0, NUM_GRAPHS=16.
// Float tensors may be stored as bf16 OR float32; batch may be int32 or int64.
// Both autodetected at runtime (deterministic per input set -> graph-safe).
// R4: wave-uniform early-out — batch is sorted, so ~91% of waves have no
// same-graph pair and can skip pos loads / sqrt / 16x v_exp_f32 entirely,
// leaving only the mandatory coalesced zero-stores.

constexpr int N    = 2048;
constexpr int NRBF = 16;

struct alignas(32) Bf16x16 { __hip_bfloat16 v[NRBF]; };
struct alignas(16) F32x4   { float v[4]; };

__device__ inline float bf16_bits_to_f32(unsigned short h) {
    union { unsigned int u; float f; } c;
    c.u = ((unsigned int)h) << 16;
    return c.f;
}

// flags[0] = 1 if float tensors are bf16, 0 if float32.
// flags[1] = 1 if batch is int64 (read low words), 0 if int32.
__global__ void detect_kernel(const unsigned int* __restrict__ posw,
                              const int*          __restrict__ batch32,
                              int*                __restrict__ flags) {
    if (blockIdx.x == 0 && threadIdx.x == 0) {
        // bf16 data: the LOW half of each 32-bit word is a genuine bf16
        // N(0,1) sample -> |v| in (1e-6, 100) essentially always.
        // float32 data: low half is random mantissa bits -> ~10% plausible.
        int cnt = 0;
        for (int k = 0; k < 16; ++k) {
            float v = bf16_bits_to_f32((unsigned short)(posw[k] & 0xFFFFu));
            float a = fabsf(v);
            if (a > 1e-6f && a < 100.0f) ++cnt;
        }
        flags[0] = (cnt >= 12) ? 1 : 0;
        // batch sorted in [0,16). int64 storage: word N-1 is a HIGH word = 0.
        // int32 storage: word N-1 = max graph id (nonzero w.p. ~1).
        flags[1] = (batch32[N - 1] == 0) ? 1 : 0;
    }
}

__global__ __launch_bounds__(256) void edge_rbf_kernel(
    const void* __restrict__ pos_raw,
    const int*  __restrict__ batch32,
    const void* __restrict__ centers_raw,
    const void* __restrict__ width_raw,
    void*       __restrict__ out_raw,
    const int*  __restrict__ flags)
{
    const int j = blockIdx.x * 256 + threadIdx.x;   // fast dim -> coalesced
    const int i = blockIdx.y;

    const bool is_bf16 = (flags[0] != 0);
    const bool b64     = (flags[1] != 0);

    const int bi = b64 ? batch32[2 * i] : batch32[i];   // little-endian low word
    const int bj = b64 ? batch32[2 * j] : batch32[j];

    // Everything below needs bi==bj and i!=j; mask/rbf are 0 otherwise.
    const bool beq = (bi == bj) && (i != j);

    const size_t pair = (size_t)i * N + j;

    if (__ballot(beq) == 0ull) {
        // Wave-uniform fast path (~91% of waves): pure zero-stores.
        if (is_bf16) {
            __hip_bfloat16* mask_out = (__hip_bfloat16*)out_raw;
            __hip_bfloat16* rbf_out  = mask_out + (size_t)N * N;
            mask_out[pair] = __float2bfloat16(0.0f);
            Bf16x16 z;
#pragma unroll
            for (int r = 0; r < NRBF; ++r) z.v[r] = __float2bfloat16(0.0f);
            *reinterpret_cast<Bf16x16*>(rbf_out + pair * NRBF) = z;
        } else {
            float* mask_out = (float*)out_raw;
            float* rbf_out  = mask_out + (size_t)N * N;
            mask_out[pair] = 0.0f;
            float* dst = rbf_out + pair * NRBF;
            F32x4 z; z.v[0] = z.v[1] = z.v[2] = z.v[3] = 0.0f;
#pragma unroll
            for (int q = 0; q < 4; ++q)
                *reinterpret_cast<F32x4*>(dst + 4 * q) = z;
        }
        return;
    }

    float xi, yi, zi, xj, yj, zj, w;
    float cen[NRBF];
    if (is_bf16) {
        const __hip_bfloat16* pos     = (const __hip_bfloat16*)pos_raw;
        const __hip_bfloat16* centers = (const __hip_bfloat16*)centers_raw;
        const __hip_bfloat16* width   = (const __hip_bfloat16*)width_raw;
        xi = __bfloat162float(pos[3 * i + 0]);
        yi = __bfloat162float(pos[3 * i + 1]);
        zi = __bfloat162float(pos[3 * i + 2]);
        xj = __bfloat162float(pos[3 * j + 0]);
        yj = __bfloat162float(pos[3 * j + 1]);
        zj = __bfloat162float(pos[3 * j + 2]);
        w  = __bfloat162float(width[0]);
#pragma unroll
        for (int r = 0; r < NRBF; ++r) cen[r] = __bfloat162float(centers[r]);
    } else {
        const float* pos     = (const float*)pos_raw;
        const float* centers = (const float*)centers_raw;
        const float* width   = (const float*)width_raw;
        xi = pos[3 * i + 0];  yi = pos[3 * i + 1];  zi = pos[3 * i + 2];
        xj = pos[3 * j + 0];  yj = pos[3 * j + 1];  zj = pos[3 * j + 2];
        w  = width[0];
#pragma unroll
        for (int r = 0; r < NRBF; ++r) cen[r] = centers[r];
    }

    // Match numpy fp32 op order exactly: no FMA contraction, IEEE sqrt.
    const float dx = __fadd_rn(__fsub_rn(xi, xj), 1e-10f);
    const float dy = __fadd_rn(__fsub_rn(yi, yj), 1e-10f);
    const float dz = __fadd_rn(__fsub_rn(zi, zj), 1e-10f);
    const float d2 = __fadd_rn(__fadd_rn(__fmul_rn(dx, dx), __fmul_rn(dy, dy)),
                               __fmul_rn(dz, dz));
    const float d  = __fsqrt_rn(d2);

    const bool  valid = beq && (d < 8.0f);
    const float ninv  = -1.0f / (2.0f * w * w);   // negated exponent scale

    float e[NRBF];
#pragma unroll
    for (int r = 0; r < NRBF; ++r) {
        const float t = d - cen[r];
        e[r] = valid ? __expf(t * t * ninv) : 0.0f;
    }

    if (is_bf16) {
        __hip_bfloat16* mask_out = (__hip_bfloat16*)out_raw;
        __hip_bfloat16* rbf_out  = mask_out + (size_t)N * N;
        mask_out[pair] = __float2bfloat16(valid ? 1.0f : 0.0f);
        Bf16x16 o;
#pragma unroll
        for (int r = 0; r < NRBF; ++r) o.v[r] = __float2bfloat16(e[r]);
        *reinterpret_cast<Bf16x16*>(rbf_out + pair * NRBF) = o;   // 32 B store
    } else {
        float* mask_out = (float*)out_raw;
        float* rbf_out  = mask_out + (size_t)N * N;
        mask_out[pair] = valid ? 1.0f : 0.0f;
        float* dst = rbf_out + pair * NRBF;                        // 64 B aligned
#pragma unroll
        for (int q = 0; q < 4; ++q) {
            F32x4 o4;
            o4.v[0] = e[4 * q + 0]; o4.v[1] = e[4 * q + 1];
            o4.v[2] = e[4 * q + 2]; o4.v[3] = e[4 * q + 3];
            *reinterpret_cast<F32x4*>(dst + 4 * q) = o4;           // dwordx4
        }
    }
}

extern "C" void kernel_launch(void* const* d_in, const int* in_sizes, int n_in,
                              void* d_out, int out_size, void* d_ws, size_t ws_size,
                              hipStream_t stream) {
    const void* pos     = d_in[0];
    const int*  batch   = (const int*)d_in[1];
    const void* centers = d_in[2];
    const void* width   = d_in[3];
    int*        flags   = (int*)d_ws;   // re-derived every call (d_ws is poisoned)

    detect_kernel<<<1, 64, 0, stream>>>((const unsigned int*)pos, batch, flags);

    dim3 grid(N / 256, N);   // j-tiles x i
    dim3 block(256);
    edge_rbf_kernel<<<grid, block, 0, stream>>>(pos, batch, centers, width,
                                                d_out, flags);
}

// Round 5
// 316.504 us; speedup vs baseline: 1.0044x; 1.0044x over previous
//
#include <hip/hip_runtime.h>
#include <hip/hip_bf16.h>

// MultiScaleEdgeBuilder: all-pairs mask + 16-wide Gaussian RBF.
// N=2048, NUM_RBF=16, CUTOFF=8.0, NUM_GRAPHS=16.
// Float tensors may be stored as bf16 OR float32; batch may be int32 or int64.
// Both autodetected at runtime from the data (deterministic per input set ->
// identical work every call, graph-safe).
// R5: single fused kernel — dtype flags derived per-block (wave-uniform, from
// L2-resident words) instead of a separate detect launch + global flags
// round-trip. Stores are the floor: 71.3M mandatory output elements.

constexpr int N    = 2048;
constexpr int NRBF = 16;

struct alignas(32) Bf16x16 { __hip_bfloat16 v[NRBF]; };
struct alignas(16) F32x4   { float v[4]; };

__device__ inline float bf16_bits_to_f32(unsigned short h) {
    union { unsigned int u; float f; } c;
    c.u = ((unsigned int)h) << 16;
    return c.f;
}

__global__ __launch_bounds__(256) void edge_rbf_kernel(
    const void* __restrict__ pos_raw,
    const int*  __restrict__ batch32,
    const void* __restrict__ centers_raw,
    const void* __restrict__ width_raw,
    void*       __restrict__ out_raw)
{
    const int j = blockIdx.x * 256 + threadIdx.x;   // fast dim -> coalesced
    const int i = blockIdx.y;

    // ---- inline dtype detection (wave-uniform; all loads L2-resident) ----
    // bf16 data: LOW half of each 32-bit word is a genuine bf16 N(0,1)
    // sample -> |v| in (1e-6, 100) essentially always. float32 data: low
    // half is random mantissa bits -> ~10% plausible. P(misclassify)~4e-9.
    const unsigned int* posw = (const unsigned int*)pos_raw;
    int cnt = 0;
#pragma unroll
    for (int k = 0; k < 16; ++k) {
        float v = bf16_bits_to_f32((unsigned short)(posw[k] & 0xFFFFu));
        float a = fabsf(v);
        if (a > 1e-6f && a < 100.0f) ++cnt;
    }
    const bool is_bf16 = (cnt >= 12);
    // batch sorted in [0,16). int64 storage: word N-1 is a HIGH word = 0.
    // int32 storage: word N-1 = max graph id (nonzero w.p. ~1).
    const bool b64 = (batch32[N - 1] == 0);

    const int bi = b64 ? batch32[2 * i] : batch32[i];   // little-endian low word
    const int bj = b64 ? batch32[2 * j] : batch32[j];

    // Everything below needs bi==bj and i!=j; mask/rbf are 0 otherwise.
    const bool beq = (bi == bj) && (i != j);

    const size_t pair = (size_t)i * N + j;

    if (__ballot(beq) == 0ull) {
        // Wave-uniform fast path (~91% of waves): pure zero-stores.
        if (is_bf16) {
            __hip_bfloat16* mask_out = (__hip_bfloat16*)out_raw;
            __hip_bfloat16* rbf_out  = mask_out + (size_t)N * N;
            mask_out[pair] = __float2bfloat16(0.0f);
            Bf16x16 z;
#pragma unroll
            for (int r = 0; r < NRBF; ++r) z.v[r] = __float2bfloat16(0.0f);
            *reinterpret_cast<Bf16x16*>(rbf_out + pair * NRBF) = z;
        } else {
            float* mask_out = (float*)out_raw;
            float* rbf_out  = mask_out + (size_t)N * N;
            mask_out[pair] = 0.0f;
            float* dst = rbf_out + pair * NRBF;
            F32x4 z; z.v[0] = z.v[1] = z.v[2] = z.v[3] = 0.0f;
#pragma unroll
            for (int q = 0; q < 4; ++q)
                *reinterpret_cast<F32x4*>(dst + 4 * q) = z;
        }
        return;
    }

    float xi, yi, zi, xj, yj, zj, w;
    float cen[NRBF];
    if (is_bf16) {
        const __hip_bfloat16* pos     = (const __hip_bfloat16*)pos_raw;
        const __hip_bfloat16* centers = (const __hip_bfloat16*)centers_raw;
        const __hip_bfloat16* width   = (const __hip_bfloat16*)width_raw;
        xi = __bfloat162float(pos[3 * i + 0]);
        yi = __bfloat162float(pos[3 * i + 1]);
        zi = __bfloat162float(pos[3 * i + 2]);
        xj = __bfloat162float(pos[3 * j + 0]);
        yj = __bfloat162float(pos[3 * j + 1]);
        zj = __bfloat162float(pos[3 * j + 2]);
        w  = __bfloat162float(width[0]);
#pragma unroll
        for (int r = 0; r < NRBF; ++r) cen[r] = __bfloat162float(centers[r]);
    } else {
        const float* pos     = (const float*)pos_raw;
        const float* centers = (const float*)centers_raw;
        const float* width   = (const float*)width_raw;
        xi = pos[3 * i + 0];  yi = pos[3 * i + 1];  zi = pos[3 * i + 2];
        xj = pos[3 * j + 0];  yj = pos[3 * j + 1];  zj = pos[3 * j + 2];
        w  = width[0];
#pragma unroll
        for (int r = 0; r < NRBF; ++r) cen[r] = centers[r];
    }

    // Match numpy fp32 op order exactly: no FMA contraction, IEEE sqrt.
    const float dx = __fadd_rn(__fsub_rn(xi, xj), 1e-10f);
    const float dy = __fadd_rn(__fsub_rn(yi, yj), 1e-10f);
    const float dz = __fadd_rn(__fsub_rn(zi, zj), 1e-10f);
    const float d2 = __fadd_rn(__fadd_rn(__fmul_rn(dx, dx), __fmul_rn(dy, dy)),
                               __fmul_rn(dz, dz));
    const float d  = __fsqrt_rn(d2);

    const bool  valid = beq && (d < 8.0f);
    const float ninv  = -1.0f / (2.0f * w * w);   // negated exponent scale

    float e[NRBF];
#pragma unroll
    for (int r = 0; r < NRBF; ++r) {
        const float t = d - cen[r];
        e[r] = valid ? __expf(t * t * ninv) : 0.0f;
    }

    if (is_bf16) {
        __hip_bfloat16* mask_out = (__hip_bfloat16*)out_raw;
        __hip_bfloat16* rbf_out  = mask_out + (size_t)N * N;
        mask_out[pair] = __float2bfloat16(valid ? 1.0f : 0.0f);
        Bf16x16 o;
#pragma unroll
        for (int r = 0; r < NRBF; ++r) o.v[r] = __float2bfloat16(e[r]);
        *reinterpret_cast<Bf16x16*>(rbf_out + pair * NRBF) = o;   // 32 B store
    } else {
        float* mask_out = (float*)out_raw;
        float* rbf_out  = mask_out + (size_t)N * N;
        mask_out[pair] = valid ? 1.0f : 0.0f;
        float* dst = rbf_out + pair * NRBF;                        // 64 B aligned
#pragma unroll
        for (int q = 0; q < 4; ++q) {
            F32x4 o4;
            o4.v[0] = e[4 * q + 0]; o4.v[1] = e[4 * q + 1];
            o4.v[2] = e[4 * q + 2]; o4.v[3] = e[4 * q + 3];
            *reinterpret_cast<F32x4*>(dst + 4 * q) = o4;           // dwordx4
        }
    }
}

extern "C" void kernel_launch(void* const* d_in, const int* in_sizes, int n_in,
                              void* d_out, int out_size, void* d_ws, size_t ws_size,
                              hipStream_t stream) {
    const void* pos     = d_in[0];
    const int*  batch   = (const int*)d_in[1];
    const void* centers = d_in[2];
    const void* width   = d_in[3];

    dim3 grid(N / 256, N);   // j-tiles x i
    dim3 block(256);
    edge_rbf_kernel<<<grid, block, 0, stream>>>(pos, batch, centers, width,
                                                d_out);
}

// Round 6
// 291.278 us; speedup vs baseline: 1.0914x; 1.0866x over previous
//
#include <hip/hip_runtime.h>
#include <hip/hip_bf16.h>

// MultiScaleEdgeBuilder: all-pairs mask + 16-wide Gaussian RBF.
// N=2048, NUM_RBF=16, CUTOFF=8.0, NUM_GRAPHS=16.
// Float tensors may be stored as bf16 OR float32; batch may be int32 or int64.
// Both autodetected at runtime from the data (graph-safe, deterministic).
//
// R6: dense wave-stores. Previous versions stored each pair's 16-element RBF
// record from one thread (lane-stride 64B/32B) -> every dwordx4 hit a
// different 64-B sector with only 16 B => 2-3x transaction overhead on the
// CU->L2 fabric. Now each wave owns 64 consecutive pairs and writes their
// 4 KB (f32) / 2 KB (bf16) record block in fully-contiguous 1-KB wave-store
// chunks (lane-stride 16 B, the fillBuffer pattern that measures 6.2 TB/s).
// Lane L computes the distance of the pair whose bytes it stores; pair
// eligibility comes from a wave ballot bitmask (no extra batch loads).

constexpr int N    = 2048;
constexpr int NRBF = 16;

struct alignas(16) Bf16x8 { __hip_bfloat16 v[8]; };
struct alignas(16) F32x4  { float v[4]; };

__device__ inline float bf16_bits_to_f32(unsigned short h) {
    union { unsigned int u; float f; } c;
    c.u = ((unsigned int)h) << 16;
    return c.f;
}

// numpy-exact fp32 distance: no FMA contraction, IEEE sqrt, ref op order.
__device__ inline float pair_dist(float xi, float yi, float zi,
                                  float xj, float yj, float zj) {
    const float dx = __fadd_rn(__fsub_rn(xi, xj), 1e-10f);
    const float dy = __fadd_rn(__fsub_rn(yi, yj), 1e-10f);
    const float dz = __fadd_rn(__fsub_rn(zi, zj), 1e-10f);
    const float d2 = __fadd_rn(__fadd_rn(__fmul_rn(dx, dx), __fmul_rn(dy, dy)),
                               __fmul_rn(dz, dz));
    return __fsqrt_rn(d2);
}

__global__ __launch_bounds__(256) void edge_rbf_kernel(
    const void* __restrict__ pos_raw,
    const int*  __restrict__ batch32,
    const void* __restrict__ centers_raw,
    const void* __restrict__ width_raw,
    void*       __restrict__ out_raw)
{
    const int lane = threadIdx.x & 63;
    const int wv   = threadIdx.x >> 6;                  // wave id in block, 0..3
    const int i    = blockIdx.y;
    const int j0   = blockIdx.x * 256 + wv * 64;        // wave's 64-pair base
    const int jL   = j0 + lane;                         // lane's own pair

    // ---- inline dtype detection (wave-uniform; L2-resident) ----
    // bf16 data: LOW half of each word is a genuine bf16 N(0,1) sample ->
    // |v| in (1e-6,100) essentially always. f32 data: random mantissa bits
    // -> ~10% plausible. P(misclassify) ~ 4e-9.
    const unsigned int* posw = (const unsigned int*)pos_raw;
    int cnt = 0;
#pragma unroll
    for (int k = 0; k < 16; ++k) {
        float v = bf16_bits_to_f32((unsigned short)(posw[k] & 0xFFFFu));
        float a = fabsf(v);
        if (a > 1e-6f && a < 100.0f) ++cnt;
    }
    const bool is_bf16 = (cnt >= 12);
    // batch sorted in [0,16). int64: word N-1 is a HIGH word = 0.
    // int32: word N-1 = max graph id (nonzero w.p. ~1).
    const bool b64 = (batch32[N - 1] == 0);

    const int bi  = b64 ? batch32[2 * i]  : batch32[i];
    const int bjL = b64 ? batch32[2 * jL] : batch32[jL];
    const bool beqL = (bi == bjL) && (i != jL);

    // bit p of 'eligible' = pair (j0+p) passes the batch & i!=j test
    const unsigned long long eligible = __ballot(beqL);

    const size_t row = (size_t)i * N;

    if (eligible == 0ull) {
        // ---- wave-uniform zero path (~91% of waves): dense zero-stores ----
        if (is_bf16) {
            __hip_bfloat16* mask_out = (__hip_bfloat16*)out_raw;
            __hip_bfloat16* rbf_out  = mask_out + (size_t)N * N;
            mask_out[row + jL] = __float2bfloat16(0.0f);      // 128 B / wave
            Bf16x8 z;
#pragma unroll
            for (int t = 0; t < 8; ++t) z.v[t] = __float2bfloat16(0.0f);
            __hip_bfloat16* base = rbf_out + (row + j0) * NRBF;
#pragma unroll
            for (int q = 0; q < 2; ++q)                        // 2 x 1 KB dense
                *reinterpret_cast<Bf16x8*>(base + q * 512 + lane * 8) = z;
        } else {
            float* mask_out = (float*)out_raw;
            float* rbf_out  = mask_out + (size_t)N * N;
            mask_out[row + jL] = 0.0f;                         // 256 B / wave
            F32x4 z; z.v[0] = z.v[1] = z.v[2] = z.v[3] = 0.0f;
            float* base = rbf_out + (row + j0) * NRBF;
#pragma unroll
            for (int q = 0; q < 4; ++q)                        // 4 x 1 KB dense
                *reinterpret_cast<F32x4*>(base + q * 256 + lane * 4) = z;
        }
        return;
    }

    // ---- valid wave: compute path ----
    float xi, yi, zi, w;
    float cen[NRBF];
    if (is_bf16) {
        const __hip_bfloat16* pos     = (const __hip_bfloat16*)pos_raw;
        const __hip_bfloat16* centers = (const __hip_bfloat16*)centers_raw;
        const __hip_bfloat16* width   = (const __hip_bfloat16*)width_raw;
        xi = __bfloat162float(pos[3 * i + 0]);
        yi = __bfloat162float(pos[3 * i + 1]);
        zi = __bfloat162float(pos[3 * i + 2]);
        w  = __bfloat162float(width[0]);
#pragma unroll
        for (int r = 0; r < NRBF; ++r) cen[r] = __bfloat162float(centers[r]);
    } else {
        const float* pos     = (const float*)pos_raw;
        const float* centers = (const float*)centers_raw;
        const float* width   = (const float*)width_raw;
        xi = pos[3 * i + 0];  yi = pos[3 * i + 1];  zi = pos[3 * i + 2];
        w  = width[0];
#pragma unroll
        for (int r = 0; r < NRBF; ++r) cen[r] = centers[r];
    }
    const float ninv = -1.0f / (2.0f * w * w);   // negated exponent scale

    // Own-pair distance for the (already dense) mask store.
    float xjL, yjL, zjL;
    if (is_bf16) {
        const __hip_bfloat16* pos = (const __hip_bfloat16*)pos_raw;
        xjL = __bfloat162float(pos[3 * jL + 0]);
        yjL = __bfloat162float(pos[3 * jL + 1]);
        zjL = __bfloat162float(pos[3 * jL + 2]);
    } else {
        const float* pos = (const float*)pos_raw;
        xjL = pos[3 * jL + 0];  yjL = pos[3 * jL + 1];  zjL = pos[3 * jL + 2];
    }
    const float dL     = pair_dist(xi, yi, zi, xjL, yjL, zjL);
    const bool  validL = beqL && (dL < 8.0f);

    if (is_bf16) {
        __hip_bfloat16* mask_out = (__hip_bfloat16*)out_raw;
        __hip_bfloat16* rbf_out  = mask_out + (size_t)N * N;
        mask_out[row + jL] = __float2bfloat16(validL ? 1.0f : 0.0f);

        const __hip_bfloat16* pos = (const __hip_bfloat16*)pos_raw;
        __hip_bfloat16* base = rbf_out + (row + j0) * NRBF;
        // Chunk q: lane L stores comps [c0,c0+8) of pair p = q*32 + L/2 at
        // byte offset q*1024 + L*16 -> dense 1-KB wave-stores.
#pragma unroll
        for (int q = 0; q < 2; ++q) {
            const int p  = q * 32 + (lane >> 1);
            const int c0 = (lane & 1) * 8;
            const int jp = j0 + p;
            const float xj = __bfloat162float(pos[3 * jp + 0]);
            const float yj = __bfloat162float(pos[3 * jp + 1]);
            const float zj = __bfloat162float(pos[3 * jp + 2]);
            const float d  = pair_dist(xi, yi, zi, xj, yj, zj);
            const bool  ok = ((eligible >> p) & 1ull) && (d < 8.0f);
            Bf16x8 o;
#pragma unroll
            for (int t = 0; t < 8; ++t) {
                const float tt = d - cen[c0 + t];
                o.v[t] = __float2bfloat16(ok ? __expf(tt * tt * ninv) : 0.0f);
            }
            *reinterpret_cast<Bf16x8*>(base + q * 512 + lane * 8) = o;
        }
    } else {
        float* mask_out = (float*)out_raw;
        float* rbf_out  = mask_out + (size_t)N * N;
        mask_out[row + jL] = validL ? 1.0f : 0.0f;

        const float* pos = (const float*)pos_raw;
        float* base = rbf_out + (row + j0) * NRBF;
        // Chunk q: lane L stores comps [c0,c0+4) of pair p = q*16 + L/4 at
        // byte offset q*1024 + L*16 -> dense 1-KB wave-stores.
#pragma unroll
        for (int q = 0; q < 4; ++q) {
            const int p  = q * 16 + (lane >> 2);
            const int c0 = (lane & 3) * 4;
            const int jp = j0 + p;
            const float xj = pos[3 * jp + 0];
            const float yj = pos[3 * jp + 1];
            const float zj = pos[3 * jp + 2];
            const float d  = pair_dist(xi, yi, zi, xj, yj, zj);
            const bool  ok = ((eligible >> p) & 1ull) && (d < 8.0f);
            F32x4 o;
#pragma unroll
            for (int t = 0; t < 4; ++t) {
                const float tt = d - cen[c0 + t];
                o.v[t] = ok ? __expf(tt * tt * ninv) : 0.0f;
            }
            *reinterpret_cast<F32x4*>(base + q * 256 + lane * 4) = o;
        }
    }
}

extern "C" void kernel_launch(void* const* d_in, const int* in_sizes, int n_in,
                              void* d_out, int out_size, void* d_ws, size_t ws_size,
                              hipStream_t stream) {
    const void* pos     = d_in[0];
    const int*  batch   = (const int*)d_in[1];
    const void* centers = d_in[2];
    const void* width   = d_in[3];

    dim3 grid(N / 256, N);   // j-tiles x i
    dim3 block(256);
    edge_rbf_kernel<<<grid, block, 0, stream>>>(pos, batch, centers, width,
                                                d_out);
}

// Round 7
// 286.521 us; speedup vs baseline: 1.1095x; 1.0166x over previous
//
#include <hip/hip_runtime.h>
#include <hip/hip_bf16.h>

// MultiScaleEdgeBuilder: all-pairs mask + 16-wide Gaussian RBF.
// N=2048, NUM_RBF=16, CUTOFF=8.0, NUM_GRAPHS=16.
// Float tensors may be stored as bf16 OR float32; batch may be int32 or int64.
// Both autodetected at runtime from the data (graph-safe, deterministic).
// Evidence so far: f32 path is the live one on this harness (R2 vs R3).
//
// R7 = R6 (dense 1-KB wave-stores, wave-uniform zero fast path) + nontemporal
// stores: the 285 MB output streams through L2 exactly once with zero reuse;
// nt stores skip L2 allocation on the pure-streaming write path.

constexpr int N    = 2048;
constexpr int NRBF = 16;

typedef float  f32x4  __attribute__((ext_vector_type(4)));
typedef short  s16x8  __attribute__((ext_vector_type(8)));

__device__ inline float bf16_bits_to_f32(unsigned short h) {
    union { unsigned int u; float f; } c;
    c.u = ((unsigned int)h) << 16;
    return c.f;
}

__device__ inline short f32_to_bf16_bits(float f) {
    __hip_bfloat16 b = __float2bfloat16(f);
    union { __hip_bfloat16 b; short s; } c; c.b = b;
    return c.s;
}

// numpy-exact fp32 distance: no FMA contraction, IEEE sqrt, ref op order.
__device__ inline float pair_dist(float xi, float yi, float zi,
                                  float xj, float yj, float zj) {
    const float dx = __fadd_rn(__fsub_rn(xi, xj), 1e-10f);
    const float dy = __fadd_rn(__fsub_rn(yi, yj), 1e-10f);
    const float dz = __fadd_rn(__fsub_rn(zi, zj), 1e-10f);
    const float d2 = __fadd_rn(__fadd_rn(__fmul_rn(dx, dx), __fmul_rn(dy, dy)),
                               __fmul_rn(dz, dz));
    return __fsqrt_rn(d2);
}

__global__ __launch_bounds__(256) void edge_rbf_kernel(
    const void* __restrict__ pos_raw,
    const int*  __restrict__ batch32,
    const void* __restrict__ centers_raw,
    const void* __restrict__ width_raw,
    void*       __restrict__ out_raw)
{
    const int lane = threadIdx.x & 63;
    const int wv   = threadIdx.x >> 6;                  // wave id in block, 0..3
    const int i    = blockIdx.y;
    const int j0   = blockIdx.x * 256 + wv * 64;        // wave's 64-pair base
    const int jL   = j0 + lane;                         // lane's own pair

    // ---- inline dtype detection (wave-uniform; L2-resident) ----
    // bf16 data: LOW half of each word is a genuine bf16 N(0,1) sample ->
    // |v| in (1e-6,100) essentially always. f32 data: low halves are zero /
    // random mantissa bits -> fails. P(misclassify) ~ 4e-9.
    const unsigned int* posw = (const unsigned int*)pos_raw;
    int cnt = 0;
#pragma unroll
    for (int k = 0; k < 16; ++k) {
        float v = bf16_bits_to_f32((unsigned short)(posw[k] & 0xFFFFu));
        float a = fabsf(v);
        if (a > 1e-6f && a < 100.0f) ++cnt;
    }
    const bool is_bf16 = (cnt >= 12);
    // batch sorted in [0,16). int64: word N-1 is a HIGH word = 0.
    // int32: word N-1 = max graph id (nonzero w.p. ~1).
    const bool b64 = (batch32[N - 1] == 0);

    const int bi  = b64 ? batch32[2 * i]  : batch32[i];
    const int bjL = b64 ? batch32[2 * jL] : batch32[jL];
    const bool beqL = (bi == bjL) && (i != jL);

    // bit p of 'eligible' = pair (j0+p) passes the batch & i!=j test
    const unsigned long long eligible = __ballot(beqL);

    const size_t row = (size_t)i * N;

    if (eligible == 0ull) {
        // ---- wave-uniform zero path (~91% of waves): dense nt zero-stores --
        if (is_bf16) {
            short* mask_out = (short*)out_raw;
            short* rbf_out  = mask_out + (size_t)N * N;
            __builtin_nontemporal_store((short)0, mask_out + row + jL);
            s16x8 z = (s16x8)0;
            short* base = rbf_out + (row + j0) * NRBF;
#pragma unroll
            for (int q = 0; q < 2; ++q)                        // 2 x 1 KB dense
                __builtin_nontemporal_store(
                    z, (s16x8*)(base + q * 512 + lane * 8));
        } else {
            float* mask_out = (float*)out_raw;
            float* rbf_out  = mask_out + (size_t)N * N;
            __builtin_nontemporal_store(0.0f, mask_out + row + jL);
            f32x4 z = (f32x4)0.0f;
            float* base = rbf_out + (row + j0) * NRBF;
#pragma unroll
            for (int q = 0; q < 4; ++q)                        // 4 x 1 KB dense
                __builtin_nontemporal_store(
                    z, (f32x4*)(base + q * 256 + lane * 4));
        }
        return;
    }

    // ---- valid wave: compute path ----
    float xi, yi, zi, w;
    float cen[NRBF];
    if (is_bf16) {
        const __hip_bfloat16* pos     = (const __hip_bfloat16*)pos_raw;
        const __hip_bfloat16* centers = (const __hip_bfloat16*)centers_raw;
        const __hip_bfloat16* width   = (const __hip_bfloat16*)width_raw;
        xi = __bfloat162float(pos[3 * i + 0]);
        yi = __bfloat162float(pos[3 * i + 1]);
        zi = __bfloat162float(pos[3 * i + 2]);
        w  = __bfloat162float(width[0]);
#pragma unroll
        for (int r = 0; r < NRBF; ++r) cen[r] = __bfloat162float(centers[r]);
    } else {
        const float* pos     = (const float*)pos_raw;
        const float* centers = (const float*)centers_raw;
        const float* width   = (const float*)width_raw;
        xi = pos[3 * i + 0];  yi = pos[3 * i + 1];  zi = pos[3 * i + 2];
        w  = width[0];
#pragma unroll
        for (int r = 0; r < NRBF; ++r) cen[r] = centers[r];
    }
    const float ninv = -1.0f / (2.0f * w * w);   // negated exponent scale

    // Own-pair distance for the (already dense) mask store.
    float xjL, yjL, zjL;
    if (is_bf16) {
        const __hip_bfloat16* pos = (const __hip_bfloat16*)pos_raw;
        xjL = __bfloat162float(pos[3 * jL + 0]);
        yjL = __bfloat162float(pos[3 * jL + 1]);
        zjL = __bfloat162float(pos[3 * jL + 2]);
    } else {
        const float* pos = (const float*)pos_raw;
        xjL = pos[3 * jL + 0];  yjL = pos[3 * jL + 1];  zjL = pos[3 * jL + 2];
    }
    const float dL     = pair_dist(xi, yi, zi, xjL, yjL, zjL);
    const bool  validL = beqL && (dL < 8.0f);

    if (is_bf16) {
        short* mask_out = (short*)out_raw;
        short* rbf_out  = mask_out + (size_t)N * N;
        __builtin_nontemporal_store(f32_to_bf16_bits(validL ? 1.0f : 0.0f),
                                    mask_out + row + jL);

        const __hip_bfloat16* pos = (const __hip_bfloat16*)pos_raw;
        short* base = rbf_out + (row + j0) * NRBF;
        // Chunk q: lane L stores comps [c0,c0+8) of pair p = q*32 + L/2 at
        // byte offset q*1024 + L*16 -> dense 1-KB wave-stores.
#pragma unroll
        for (int q = 0; q < 2; ++q) {
            const int p  = q * 32 + (lane >> 1);
            const int c0 = (lane & 1) * 8;
            const int jp = j0 + p;
            const float xj = __bfloat162float(pos[3 * jp + 0]);
            const float yj = __bfloat162float(pos[3 * jp + 1]);
            const float zj = __bfloat162float(pos[3 * jp + 2]);
            const float d  = pair_dist(xi, yi, zi, xj, yj, zj);
            const bool  ok = ((eligible >> p) & 1ull) && (d < 8.0f);
            s16x8 o;
#pragma unroll
            for (int t = 0; t < 8; ++t) {
                const float tt = d - cen[c0 + t];
                o[t] = f32_to_bf16_bits(ok ? __expf(tt * tt * ninv) : 0.0f);
            }
            __builtin_nontemporal_store(o, (s16x8*)(base + q * 512 + lane * 8));
        }
    } else {
        float* mask_out = (float*)out_raw;
        float* rbf_out  = mask_out + (size_t)N * N;
        __builtin_nontemporal_store(validL ? 1.0f : 0.0f, mask_out + row + jL);

        const float* pos = (const float*)pos_raw;
        float* base = rbf_out + (row + j0) * NRBF;
        // Chunk q: lane L stores comps [c0,c0+4) of pair p = q*16 + L/4 at
        // byte offset q*1024 + L*16 -> dense 1-KB wave-stores.
#pragma unroll
        for (int q = 0; q < 4; ++q) {
            const int p  = q * 16 + (lane >> 2);
            const int c0 = (lane & 3) * 4;
            const int jp = j0 + p;
            const float xj = pos[3 * jp + 0];
            const float yj = pos[3 * jp + 1];
            const float zj = pos[3 * jp + 2];
            const float d  = pair_dist(xi, yi, zi, xj, yj, zj);
            const bool  ok = ((eligible >> p) & 1ull) && (d < 8.0f);
            f32x4 o;
#pragma unroll
            for (int t = 0; t < 4; ++t) {
                const float tt = d - cen[c0 + t];
                o[t] = ok ? __expf(tt * tt * ninv) : 0.0f;
            }
            __builtin_nontemporal_store(o, (f32x4*)(base + q * 256 + lane * 4));
        }
    }
}

extern "C" void kernel_launch(void* const* d_in, const int* in_sizes, int n_in,
                              void* d_out, int out_size, void* d_ws, size_t ws_size,
                              hipStream_t stream) {
    const void* pos     = d_in[0];
    const int*  batch   = (const int*)d_in[1];
    const void* centers = d_in[2];
    const void* width   = d_in[3];

    dim3 grid(N / 256, N);   // j-tiles x i
    dim3 block(256);
    edge_rbf_kernel<<<grid, block, 0, stream>>>(pos, batch, centers, width,
                                                d_out);
}